// Round 3
// baseline (1659.714 us; speedup 1.0000x reference)
//
#include <hip/hip_runtime.h>
#include <hip/hip_bf16.h>
#include <stdint.h>

typedef __hip_bfloat16 bf16;
typedef unsigned short u16;
typedef unsigned int u32;
typedef __bf16 v8bf __attribute__((ext_vector_type(8)));
typedef float v4f __attribute__((ext_vector_type(4)));

// Problem constants
#define NB 16384            // B
#define MROWS 147456        // T*B*3 token rows

__device__ __forceinline__ float b2f(u16 u) {
  union { u32 u; float f; } v; v.u = ((u32)u) << 16; return v.f;
}
__device__ __forceinline__ u16 f2b(float f) {
  union { float f; u32 u; } v; v.f = f;
  u32 u = v.u;
  return (u16)((u + 0x7fffu + ((u >> 16) & 1u)) >> 16);
}
__device__ __forceinline__ void async16(const u16* g, u16* lds) {
  __builtin_amdgcn_global_load_lds((const __attribute__((address_space(1))) void*)g,
                                   (__attribute__((address_space(3))) void*)lds,
                                   16, 0, 0);
}

// ---------------------------------------------------------------------------
// Weight prep: read f32 weights, write transposed bf16 [N][K] (gemm_bt form);
// pack bq/bk/bv contiguously as f32. Per-layer element layout in wt:
// q 0, k 65536, v 131072, o 196608, W1T 262144 (1024x256),
// W2T 524288 (256x1024); layer stride 786432 elements.
// ---------------------------------------------------------------------------
__global__ __launch_bounds__(256)
void prep_weights(const float* Wq, const float* Wk, const float* Wv, const float* Wo,
                  const float* W1, const float* W2,
                  const float* bq, const float* bk, const float* bv,
                  bf16* wt, float* bqkv)
{
  if (blockIdx.x == 6144) {   // bias-pack block
    for (int e = threadIdx.x; e < 1536; e += 256) {
      int l = e / 768;
      int rem = e - l * 768;
      int wsel = rem >> 8;
      int col = rem & 255;
      const float* s = (wsel == 0) ? bq : (wsel == 1) ? bk : bv;
      bqkv[e] = s[l * 256 + col];
    }
    return;
  }
  int gid = blockIdx.x * 256 + threadIdx.x;   // [0, 1572864)
  int layer = (gid >= 786432) ? 1 : 0;
  int r = gid - layer * 786432;
  const float* src; int K, N, e, outoff;
  if (r < 262144) {
    int which = r >> 16;
    e = r & 65535; K = 256; N = 256;
    const float* w = (which == 0) ? Wq : (which == 1) ? Wk : (which == 2) ? Wv : Wo;
    src = w + layer * 65536;
    outoff = layer * 786432 + which * 65536;
  } else if (r < 524288) {
    e = r - 262144; K = 256; N = 1024;
    src = W1 + layer * 262144;
    outoff = layer * 786432 + 262144;
  } else {
    e = r - 524288; K = 1024; N = 256;
    src = W2 + layer * 262144;
    outoff = layer * 786432 + 524288;
  }
  int n = e / K, kk = e - n * K;
  ((u16*)wt)[outoff + e] = f2b(src[kk * N + n]);
}

// ---------------------------------------------------------------------------
// Graph message build (f32 in, f32 out): global row = row0 + local row.
// row = n*3 + t, n = term*B + b. t==2 -> self; else per fixed edge table.
// ---------------------------------------------------------------------------
__global__ __launch_bounds__(256)
void build_x(const float* __restrict__ T, const float* __restrict__ P,
             float* __restrict__ X, int row0)
{
  int tid = blockIdx.x * 256 + threadIdx.x;   // 4 f32 per thread
  int lrow = tid >> 6;
  int d0 = (tid & 63) * 4;
  int row = row0 + lrow;
  int n = row / 3;
  int t = row - n * 3;
  size_t xoff = (size_t)lrow * 256 + d0;
  if (t == 2) {
    *(float4*)(X + xoff) = *(const float4*)(T + (size_t)n * 256 + d0);
    return;
  }
  int tm = n >> 14, b = n & 16383;
  const int srcT[6] = {1, 2,  0, 2,  1, 0};
  const int srcP[6] = {0, 2,  0, 1,  1, 2};
  const float sg[6] = {-1.f, -1.f,  1.f, -1.f,  1.f, 1.f};
  int idx = tm * 2 + t;
  float4 tv = *(const float4*)(T + ((size_t)(srcT[idx] * NB + b)) * 256 + d0);
  float4 pv = *(const float4*)(P + ((size_t)(srcP[idx] * NB + b)) * 256 + d0);
  float s = sg[idx];
  float4 ov;
  ov.x = tv.x + s * pv.x;
  ov.y = tv.y + s * pv.y;
  ov.z = tv.z + s * pv.z;
  ov.w = tv.w + s * pv.w;
  *(float4*)(X + xoff) = ov;
}

// ---------------------------------------------------------------------------
// LayerNorm over D=256 (f32 in, bf16 out). 1 wave per row, 4 rows per block.
// ---------------------------------------------------------------------------
__global__ __launch_bounds__(256)
void ln_rows(const float* __restrict__ xp, const float* __restrict__ gp,
             const float* __restrict__ bp, bf16* __restrict__ hp)
{
  const int lane = threadIdx.x & 63;
  const int row = blockIdx.x * 4 + (threadIdx.x >> 6);
  float4 rv = *(const float4*)(xp + (size_t)row * 256 + lane * 4);
  float v0 = rv.x, v1 = rv.y, v2 = rv.z, v3 = rv.w;
  float s = v0 + v1 + v2 + v3;
  float q = v0 * v0 + v1 * v1 + v2 * v2 + v3 * v3;
  #pragma unroll
  for (int m = 32; m > 0; m >>= 1) {
    s += __shfl_xor(s, m, 64);
    q += __shfl_xor(q, m, 64);
  }
  float mean = s * (1.f / 256.f);
  float var = q * (1.f / 256.f) - mean * mean;
  float r = rsqrtf(var + 1e-5f);
  float4 gv = *(const float4*)(gp + lane * 4);
  float4 bv = *(const float4*)(bp + lane * 4);
  ushort4 outv;
  outv.x = f2b((v0 - mean) * r * gv.x + bv.x);
  outv.y = f2b((v1 - mean) * r * gv.y + bv.y);
  outv.z = f2b((v2 - mean) * r * gv.z + bv.z);
  outv.w = f2b((v3 - mean) * r * gv.w + bv.w);
  *(ushort4*)((u16*)hp + (size_t)row * 256 + lane * 4) = outv;
}

// ---------------------------------------------------------------------------
// GEMM: C[M,N] = A[M,K] @ Bt[N,K]^T (+bias[col]) (+res) (+relu).
// A,Bt bf16; bias f32; res f32; C bf16 or f32 (OUTF32). fp32 MFMA accumulate.
// 128x128 tile, 4 waves, 4x4 of 16x16x32 per wave, BK=32,
// global_load_lds width-16 staging. blockIdx.z selects weight/bias/out set.
// ---------------------------------------------------------------------------
template<int RES, int RELU, int OUTF32>
__global__ __launch_bounds__(256)
void gemm_bt(const bf16* __restrict__ Ap, const bf16* __restrict__ Btp,
             const float* __restrict__ biasp, const float* __restrict__ resp,
             void* __restrict__ Cp, int N, int K,
             int btZ, int biasZ, long long cZ)
{
  __shared__ __align__(16) u16 As[128 * 32];
  __shared__ __align__(16) u16 Bs[128 * 32];
  const int z = blockIdx.z;
  const u16* A = (const u16*)Ap;
  const u16* Bt = (const u16*)Btp + (size_t)z * btZ;
  const float* bias = biasp + (size_t)z * biasZ;
  const int m0 = blockIdx.x * 128;
  const int n0 = blockIdx.y * 128;
  const int tid = threadIdx.x;
  const int w = tid >> 6, lane = tid & 63;
  const int waveM = (w & 1) * 64, waveN = (w >> 1) * 64;

  const int rrow = tid >> 2;          // 0..63
  const int kcol = (tid & 3) * 8;
  const u16* pA0 = A + (size_t)(m0 + rrow) * K + kcol;
  const u16* pA1 = A + (size_t)(m0 + rrow + 64) * K + kcol;
  const u16* pB0 = Bt + (size_t)(n0 + rrow) * K + kcol;
  const u16* pB1 = Bt + (size_t)(n0 + rrow + 64) * K + kcol;
  u16* lA0 = As + w * 512;            // wave-uniform LDS bases
  u16* lA1 = As + 2048 + w * 512;
  u16* lB0 = Bs + w * 512;
  u16* lB1 = Bs + 2048 + w * 512;

  v4f acc[4][4];
  #pragma unroll
  for (int i = 0; i < 4; i++)
    #pragma unroll
    for (int j = 0; j < 4; j++) {
      v4f zz = {0.f, 0.f, 0.f, 0.f};
      acc[i][j] = zz;
    }

  const char* AsC = (const char*)As;
  const char* BsC = (const char*)Bs;
  const int rdA = (waveM + (lane & 15)) * 64 + (lane >> 4) * 16;
  const int rdB = (waveN + (lane & 15)) * 64 + (lane >> 4) * 16;

  for (int kt = 0; kt < K; kt += 32) {
    __syncthreads();
    async16(pA0, lA0); async16(pA1, lA1);
    async16(pB0, lB0); async16(pB1, lB1);
    pA0 += 32; pA1 += 32; pB0 += 32; pB1 += 32;
    __syncthreads();
    v8bf a[4], b[4];
    #pragma unroll
    for (int i = 0; i < 4; i++)
      a[i] = *(const v8bf*)(AsC + rdA + i * 1024);
    #pragma unroll
    for (int j = 0; j < 4; j++)
      b[j] = *(const v8bf*)(BsC + rdB + j * 1024);
    #pragma unroll
    for (int i = 0; i < 4; i++)
      #pragma unroll
      for (int j = 0; j < 4; j++)
        acc[i][j] = __builtin_amdgcn_mfma_f32_16x16x32_bf16(a[i], b[j], acc[i][j], 0, 0, 0);
  }

  float bv[4];
  #pragma unroll
  for (int j = 0; j < 4; j++)
    bv[j] = bias[n0 + waveN + j * 16 + (lane & 15)];

  #pragma unroll
  for (int i = 0; i < 4; i++) {
    #pragma unroll
    for (int r = 0; r < 4; r++) {
      int rowg = m0 + waveM + i * 16 + (lane >> 4) * 4 + r;
      size_t rb = (size_t)rowg * N;
      #pragma unroll
      for (int j = 0; j < 4; j++) {
        int colg = n0 + waveN + j * 16 + (lane & 15);
        float vv = acc[i][j][r] + bv[j];
        if (RES) vv += resp[rb + colg];
        if (RELU) vv = fmaxf(vv, 0.f);
        if (OUTF32) ((float*)Cp)[rb + colg] = vv;
        else ((u16*)Cp + (size_t)z * cZ)[rb + colg] = f2b(vv);
      }
    }
  }
}

// ---------------------------------------------------------------------------
// Attention: seq_len 3, H=8, DH=32, bf16 in/out. 8 sequences per block.
// ---------------------------------------------------------------------------
__global__ __launch_bounds__(256)
void attn(const bf16* __restrict__ qp, const bf16* __restrict__ kp,
          const bf16* __restrict__ vp, bf16* __restrict__ op)
{
  __shared__ __align__(16) u16 qs[6144], ks[6144], vs[6144];
  __shared__ float probs[8][8][9];
  const int tid = threadIdx.x;
  const size_t gbase = (size_t)blockIdx.x * 6144;   // 8 seq * 3 tok * 256
  const uint4* qg = (const uint4*)((const u16*)qp + gbase);
  const uint4* kg = (const uint4*)((const u16*)kp + gbase);
  const uint4* vg = (const uint4*)((const u16*)vp + gbase);
  for (int c = tid; c < 768; c += 256) {
    ((uint4*)qs)[c] = qg[c];
    ((uint4*)ks)[c] = kg[c];
    ((uint4*)vs)[c] = vg[c];
  }
  __syncthreads();
  if (tid < 64) {
    int s = tid >> 3, h = tid & 7;
    int base = s * 768 + h * 32;
    float sc[3][3];
    #pragma unroll
    for (int i = 0; i < 3; i++)
      #pragma unroll
      for (int j = 0; j < 3; j++) {
        float sum = 0.f;
        #pragma unroll
        for (int d = 0; d < 32; d++)
          sum += b2f(qs[base + i * 256 + d]) * b2f(ks[base + j * 256 + d]);
        sc[i][j] = sum * 0.17677669529663687f;   // DH^-0.5
      }
    #pragma unroll
    for (int i = 0; i < 3; i++) {
      float m = fmaxf(sc[i][0], fmaxf(sc[i][1], sc[i][2]));
      float e0 = __expf(sc[i][0] - m);
      float e1 = __expf(sc[i][1] - m);
      float e2 = __expf(sc[i][2] - m);
      float inv = 1.f / (e0 + e1 + e2);
      probs[s][h][i * 3 + 0] = e0 * inv;
      probs[s][h][i * 3 + 1] = e1 * inv;
      probs[s][h][i * 3 + 2] = e2 * inv;
    }
  }
  __syncthreads();
  u16* og = (u16*)op + gbase;
  for (int c = tid; c < 6144; c += 256) {
    int lrow = c >> 8, hd = c & 255;
    int s = lrow / 3, i = lrow - s * 3;
    int h = hd >> 5;
    float p0 = probs[s][h][i * 3 + 0];
    float p1 = probs[s][h][i * 3 + 1];
    float p2 = probs[s][h][i * 3 + 2];
    float o = p0 * b2f(vs[s * 768 + hd])
            + p1 * b2f(vs[s * 768 + 256 + hd])
            + p2 * b2f(vs[s * 768 + 512 + hd]);
    og[c] = f2b(o);
  }
}

// ---------------------------------------------------------------------------
// Final LN + mean over 3 tokens (f32 in, f32 out). 1 wave/seq, 4 seq/block.
// ---------------------------------------------------------------------------
__global__ __launch_bounds__(256)
void ln_final_mean(const float* __restrict__ xp, const float* __restrict__ gp,
                   const float* __restrict__ bp, float* __restrict__ outp)
{
  const int lane = threadIdx.x & 63;
  const int n = blockIdx.x * 4 + (threadIdx.x >> 6);
  float4 gv = *(const float4*)(gp + lane * 4);
  float4 bv4 = *(const float4*)(bp + lane * 4);
  float a0 = 0.f, a1 = 0.f, a2 = 0.f, a3 = 0.f;
  for (int t = 0; t < 3; t++) {
    float4 rv = *(const float4*)(xp + ((size_t)n * 3 + t) * 256 + lane * 4);
    float v0 = rv.x, v1 = rv.y, v2 = rv.z, v3 = rv.w;
    float s = v0 + v1 + v2 + v3;
    float q = v0 * v0 + v1 * v1 + v2 * v2 + v3 * v3;
    #pragma unroll
    for (int m = 32; m > 0; m >>= 1) {
      s += __shfl_xor(s, m, 64);
      q += __shfl_xor(q, m, 64);
    }
    float mean = s * (1.f / 256.f);
    float var = q * (1.f / 256.f) - mean * mean;
    float r = rsqrtf(var + 1e-5f);
    a0 += (v0 - mean) * r * gv.x + bv4.x;
    a1 += (v1 - mean) * r * gv.y + bv4.y;
    a2 += (v2 - mean) * r * gv.z + bv4.z;
    a3 += (v3 - mean) * r * gv.w + bv4.w;
  }
  const float third = 1.f / 3.f;
  float4 outv;
  outv.x = a0 * third;
  outv.y = a1 * third;
  outv.z = a2 * third;
  outv.w = a3 * third;
  *(float4*)(outp + (size_t)n * 256 + lane * 4) = outv;
}

// ---------------------------------------------------------------------------
extern "C" void kernel_launch(void* const* d_in, const int* in_sizes, int n_in,
                              void* d_out, int out_size, void* d_ws, size_t ws_size,
                              hipStream_t stream)
{
  const float* term = (const float*)d_in[0];
  const float* pred = (const float*)d_in[1];
  const float* Wq  = (const float*)d_in[2];
  const float* Wk  = (const float*)d_in[3];
  const float* Wv  = (const float*)d_in[4];
  const float* Wo  = (const float*)d_in[5];
  const float* bq  = (const float*)d_in[6];
  const float* bk  = (const float*)d_in[7];
  const float* bvv = (const float*)d_in[8];
  const float* bo  = (const float*)d_in[9];
  const float* ln1g = (const float*)d_in[10];
  const float* ln1b = (const float*)d_in[11];
  const float* ln2g = (const float*)d_in[12];
  const float* ln2b = (const float*)d_in[13];
  const float* W1  = (const float*)d_in[14];
  const float* b1  = (const float*)d_in[15];
  const float* W2  = (const float*)d_in[16];
  const float* b2  = (const float*)d_in[17];
  const float* lnfg = (const float*)d_in[18];
  const float* lnfb = (const float*)d_in[19];

  // --- choose chunk count from ws_size (deterministic; same every call).
  // Per chunk: x f32 (Mc*1024B) + h bf16 (Mc*512B) + q,k,v,o bf16 (Mc*2048B,
  // f aliases q..o). Weights/bias: 4 MB up front.
  int nch = 128;
  for (int c = 1; c <= 128; c *= 2) {
    size_t Mc = (size_t)MROWS / c;
    size_t need = 4ull * 1024 * 1024 + Mc * 3584ull;
    if (need <= ws_size) { nch = c; break; }
  }
  const size_t Mc = (size_t)MROWS / nch;     // multiple of 1152
  const int mBlocks = (int)(Mc / 128);

  char* ws = (char*)d_ws;
  bf16* wt   = (bf16*)ws;                    // 1572864 el (3 MB)
  float* bqkv = (float*)(ws + 3145728);      // 1536 f32
  float* x = (float*)(ws + 4194304);         // Mc*256 f32
  bf16* h = (bf16*)(x + Mc * 256);           // Mc*256 bf16
  bf16* q = h + Mc * 256;                    // q,k,v,o contiguous bf16
  bf16* v_ = q + 2 * Mc * 256;
  bf16* o = q + 3 * Mc * 256;
  bf16* f = q;                               // FFN hidden aliases q..o

  prep_weights<<<6145, 256, 0, stream>>>(Wq, Wk, Wv, Wo, W1, W2, bq, bk, bvv, wt, bqkv);

  const long long qkvZ = (long long)(Mc * 256);
  for (int ch = 0; ch < nch; ch++) {
    const int row0 = (int)(ch * Mc);
    build_x<<<(int)(Mc / 4), 256, 0, stream>>>(term, pred, x, row0);
    for (int l = 0; l < 2; l++) {
      const bf16* wl = wt + l * 786432;
      ln_rows<<<(int)(Mc / 4), 256, 0, stream>>>(x, ln1g + l * 256, ln1b + l * 256, h);
      gemm_bt<0, 0, 0><<<dim3(mBlocks, 2, 3), 256, 0, stream>>>(
          h, wl, bqkv + l * 768, nullptr, q, 256, 256, 65536, 256, qkvZ);
      attn<<<(int)(Mc / 24), 256, 0, stream>>>(q, q + Mc * 256, v_, o);
      gemm_bt<1, 0, 1><<<dim3(mBlocks, 2, 1), 256, 0, stream>>>(
          o, wl + 196608, bo + l * 256, x, x, 256, 256, 0, 0, 0);
      ln_rows<<<(int)(Mc / 4), 256, 0, stream>>>(x, ln2g + l * 256, ln2b + l * 256, h);
      gemm_bt<0, 1, 0><<<dim3(mBlocks, 8, 1), 256, 0, stream>>>(
          h, wl + 262144, b1 + l * 1024, nullptr, f, 1024, 256, 0, 0, 0);
      gemm_bt<1, 0, 1><<<dim3(mBlocks, 2, 1), 256, 0, stream>>>(
          f, wl + 524288, b2 + l * 256, x, x, 256, 1024, 0, 0, 0);
    }
    ln_final_mean<<<(int)(Mc / 12), 256, 0, stream>>>(
        x, lnfg, lnfb, (float*)d_out + (size_t)(row0 / 3) * 256);
  }
}

// Round 4
// 1591.545 us; speedup vs baseline: 1.0428x; 1.0428x over previous
//
#include <hip/hip_runtime.h>
#include <hip/hip_bf16.h>
#include <stdint.h>

typedef __hip_bfloat16 bf16;
typedef unsigned short u16;
typedef unsigned int u32;
typedef __bf16 v8bf __attribute__((ext_vector_type(8)));
typedef float v4f __attribute__((ext_vector_type(4)));

// Problem constants
#define NB 16384            // B
#define MROWS 147456        // T*B*3 token rows

__device__ __forceinline__ float b2f(u16 u) {
  union { u32 u; float f; } v; v.u = ((u32)u) << 16; return v.f;
}
__device__ __forceinline__ u16 f2b(float f) {
  union { float f; u32 u; } v; v.f = f;
  u32 u = v.u;
  return (u16)((u + 0x7fffu + ((u >> 16) & 1u)) >> 16);
}
__device__ __forceinline__ void async16(const u16* g, u16* lds) {
  __builtin_amdgcn_global_load_lds((const __attribute__((address_space(1))) void*)g,
                                   (__attribute__((address_space(3))) void*)lds,
                                   16, 0, 0);
}

// ---------------------------------------------------------------------------
// Weight prep: read f32 weights, write transposed bf16 [N][K] (gemm_bt form);
// pack bq/bk/bv contiguously as f32. Per-layer element layout in wt:
// q 0, k 65536, v 131072, o 196608, W1T 262144 (1024x256),
// W2T 524288 (256x1024); layer stride 786432 elements.
// ---------------------------------------------------------------------------
__global__ __launch_bounds__(256)
void prep_weights(const float* Wq, const float* Wk, const float* Wv, const float* Wo,
                  const float* W1, const float* W2,
                  const float* bq, const float* bk, const float* bv,
                  bf16* wt, float* bqkv)
{
  if (blockIdx.x == 6144) {   // bias-pack block
    for (int e = threadIdx.x; e < 1536; e += 256) {
      int l = e / 768;
      int rem = e - l * 768;
      int wsel = rem >> 8;
      int col = rem & 255;
      const float* s = (wsel == 0) ? bq : (wsel == 1) ? bk : bv;
      bqkv[e] = s[l * 256 + col];
    }
    return;
  }
  int gid = blockIdx.x * 256 + threadIdx.x;   // [0, 1572864)
  int layer = (gid >= 786432) ? 1 : 0;
  int r = gid - layer * 786432;
  const float* src; int K, N, e, outoff;
  if (r < 262144) {
    int which = r >> 16;
    e = r & 65535; K = 256; N = 256;
    const float* w = (which == 0) ? Wq : (which == 1) ? Wk : (which == 2) ? Wv : Wo;
    src = w + layer * 65536;
    outoff = layer * 786432 + which * 65536;
  } else if (r < 524288) {
    e = r - 262144; K = 256; N = 1024;
    src = W1 + layer * 262144;
    outoff = layer * 786432 + 262144;
  } else {
    e = r - 524288; K = 1024; N = 256;
    src = W2 + layer * 262144;
    outoff = layer * 786432 + 524288;
  }
  int n = e / K, kk = e - n * K;
  ((u16*)wt)[outoff + e] = f2b(src[kk * N + n]);
}

// ---------------------------------------------------------------------------
// Fused graph-message build + layer-0 LN1: compute x row, write x (f32),
// LayerNorm it, write h (bf16). 1 wave per row, 4 rows per block.
// ---------------------------------------------------------------------------
__global__ __launch_bounds__(256)
void build_ln(const float* __restrict__ T, const float* __restrict__ P,
              const float* __restrict__ gp, const float* __restrict__ bp,
              float* __restrict__ X, bf16* __restrict__ H, int row0)
{
  const int lane = threadIdx.x & 63;
  const int lrow = blockIdx.x * 4 + (threadIdx.x >> 6);
  const int row = row0 + lrow;
  const int d0 = lane * 4;
  int n = row / 3;
  int t = row - n * 3;
  float4 v;
  if (t == 2) {
    v = *(const float4*)(T + (size_t)n * 256 + d0);
  } else {
    int tm = n >> 14, b = n & 16383;
    const int srcT[6] = {1, 2,  0, 2,  1, 0};
    const int srcP[6] = {0, 2,  0, 1,  1, 2};
    const float sg[6] = {-1.f, -1.f,  1.f, -1.f,  1.f, 1.f};
    int idx = tm * 2 + t;
    float4 tv = *(const float4*)(T + ((size_t)(srcT[idx] * NB + b)) * 256 + d0);
    float4 pv = *(const float4*)(P + ((size_t)(srcP[idx] * NB + b)) * 256 + d0);
    float s = sg[idx];
    v.x = tv.x + s * pv.x;
    v.y = tv.y + s * pv.y;
    v.z = tv.z + s * pv.z;
    v.w = tv.w + s * pv.w;
  }
  *(float4*)(X + (size_t)lrow * 256 + d0) = v;
  float s = v.x + v.y + v.z + v.w;
  float q = v.x * v.x + v.y * v.y + v.z * v.z + v.w * v.w;
  #pragma unroll
  for (int m = 32; m > 0; m >>= 1) {
    s += __shfl_xor(s, m, 64);
    q += __shfl_xor(q, m, 64);
  }
  float mean = s * (1.f / 256.f);
  float var = q * (1.f / 256.f) - mean * mean;
  float r = rsqrtf(var + 1e-5f);
  float4 gv = *(const float4*)(gp + d0);
  float4 bv = *(const float4*)(bp + d0);
  ushort4 outv;
  outv.x = f2b((v.x - mean) * r * gv.x + bv.x);
  outv.y = f2b((v.y - mean) * r * gv.y + bv.y);
  outv.z = f2b((v.z - mean) * r * gv.z + bv.z);
  outv.w = f2b((v.w - mean) * r * gv.w + bv.w);
  *(ushort4*)((u16*)H + (size_t)lrow * 256 + d0) = outv;
}

// ---------------------------------------------------------------------------
// LayerNorm over D=256 (f32 in, bf16 out). 1 wave per row, 4 rows per block.
// ---------------------------------------------------------------------------
__global__ __launch_bounds__(256)
void ln_rows(const float* __restrict__ xp, const float* __restrict__ gp,
             const float* __restrict__ bp, bf16* __restrict__ hp)
{
  const int lane = threadIdx.x & 63;
  const int row = blockIdx.x * 4 + (threadIdx.x >> 6);
  float4 rv = *(const float4*)(xp + (size_t)row * 256 + lane * 4);
  float v0 = rv.x, v1 = rv.y, v2 = rv.z, v3 = rv.w;
  float s = v0 + v1 + v2 + v3;
  float q = v0 * v0 + v1 * v1 + v2 * v2 + v3 * v3;
  #pragma unroll
  for (int m = 32; m > 0; m >>= 1) {
    s += __shfl_xor(s, m, 64);
    q += __shfl_xor(q, m, 64);
  }
  float mean = s * (1.f / 256.f);
  float var = q * (1.f / 256.f) - mean * mean;
  float r = rsqrtf(var + 1e-5f);
  float4 gv = *(const float4*)(gp + lane * 4);
  float4 bv = *(const float4*)(bp + lane * 4);
  ushort4 outv;
  outv.x = f2b((v0 - mean) * r * gv.x + bv.x);
  outv.y = f2b((v1 - mean) * r * gv.y + bv.y);
  outv.z = f2b((v2 - mean) * r * gv.z + bv.z);
  outv.w = f2b((v3 - mean) * r * gv.w + bv.w);
  *(ushort4*)((u16*)hp + (size_t)row * 256 + lane * 4) = outv;
}

// ---------------------------------------------------------------------------
// GEMM: C[M,N] = A[M,K] @ Bt[N,K]^T (+bias[col]) (+res) (+relu).
// A,Bt bf16; bias f32; res f32; C bf16 or f32 (OUTF32). fp32 MFMA accumulate.
// 128x128 tile, 4 waves, 4x4 of 16x16x32 per wave, BK=32.
// DOUBLE-BUFFERED global_load_lds staging: one barrier per K-iter; next
// tile's loads are issued before computing the current tile, so global
// latency overlaps the MFMA+ds_read work (the round-3 version exposed the
// full load latency at 2 barriers/iter -> 31% HBM, 14% MfmaUtil).
// ---------------------------------------------------------------------------
template<int RES, int RELU, int OUTF32>
__global__ __launch_bounds__(256)
void gemm_bt(const bf16* __restrict__ Ap, const bf16* __restrict__ Btp,
             const float* __restrict__ biasp, const float* __restrict__ resp,
             void* __restrict__ Cp, int N, int K,
             int btZ, int biasZ, long long cZ)
{
  __shared__ __align__(16) u16 As[2 * 128 * 32];
  __shared__ __align__(16) u16 Bs[2 * 128 * 32];
  const int z = blockIdx.z;
  const u16* A = (const u16*)Ap;
  const u16* Bt = (const u16*)Btp + (size_t)z * btZ;
  const float* bias = biasp + (size_t)z * biasZ;
  const int m0 = blockIdx.x * 128;
  const int n0 = blockIdx.y * 128;
  const int tid = threadIdx.x;
  const int w = tid >> 6, lane = tid & 63;
  const int waveM = (w & 1) * 64, waveN = (w >> 1) * 64;

  const int rrow = tid >> 2;          // 0..63
  const int kcol = (tid & 3) * 8;
  const u16* pA0 = A + (size_t)(m0 + rrow) * K + kcol;
  const u16* pA1 = A + (size_t)(m0 + rrow + 64) * K + kcol;
  const u16* pB0 = Bt + (size_t)(n0 + rrow) * K + kcol;
  const u16* pB1 = Bt + (size_t)(n0 + rrow + 64) * K + kcol;

  v4f acc[4][4];
  #pragma unroll
  for (int i = 0; i < 4; i++)
    #pragma unroll
    for (int j = 0; j < 4; j++) {
      v4f zz = {0.f, 0.f, 0.f, 0.f};
      acc[i][j] = zz;
    }

  const int rdA = (waveM + (lane & 15)) * 64 + (lane >> 4) * 16;  // byte offs
  const int rdB = (waveN + (lane & 15)) * 64 + (lane >> 4) * 16;
  const int nk = K >> 5;

  // preload tile 0 into buffer 0
  async16(pA0, As + w * 512);        async16(pA1, As + 2048 + w * 512);
  async16(pB0, Bs + w * 512);        async16(pB1, Bs + 2048 + w * 512);
  pA0 += 32; pA1 += 32; pB0 += 32; pB1 += 32;

  int cur = 0;
  for (int kt = 0; kt < nk; kt++) {
    __syncthreads();                  // buf[cur] loads complete & visible
    if (kt + 1 < nk) {
      const int nxt = (cur ^ 1) * 4096;
      async16(pA0, As + nxt + w * 512);        async16(pA1, As + nxt + 2048 + w * 512);
      async16(pB0, Bs + nxt + w * 512);        async16(pB1, Bs + nxt + 2048 + w * 512);
      pA0 += 32; pA1 += 32; pB0 += 32; pB1 += 32;
    }
    const char* AsC = (const char*)(As + cur * 4096);
    const char* BsC = (const char*)(Bs + cur * 4096);
    v8bf a[4], b[4];
    #pragma unroll
    for (int i = 0; i < 4; i++)
      a[i] = *(const v8bf*)(AsC + rdA + i * 1024);
    #pragma unroll
    for (int j = 0; j < 4; j++)
      b[j] = *(const v8bf*)(BsC + rdB + j * 1024);
    #pragma unroll
    for (int i = 0; i < 4; i++)
      #pragma unroll
      for (int j = 0; j < 4; j++)
        acc[i][j] = __builtin_amdgcn_mfma_f32_16x16x32_bf16(a[i], b[j], acc[i][j], 0, 0, 0);
    cur ^= 1;
  }

  float bv[4];
  #pragma unroll
  for (int j = 0; j < 4; j++)
    bv[j] = bias[n0 + waveN + j * 16 + (lane & 15)];

  #pragma unroll
  for (int i = 0; i < 4; i++) {
    #pragma unroll
    for (int r = 0; r < 4; r++) {
      int rowg = m0 + waveM + i * 16 + (lane >> 4) * 4 + r;
      size_t rb = (size_t)rowg * N;
      #pragma unroll
      for (int j = 0; j < 4; j++) {
        int colg = n0 + waveN + j * 16 + (lane & 15);
        float vv = acc[i][j][r] + bv[j];
        if (RES) vv += resp[rb + colg];
        if (RELU) vv = fmaxf(vv, 0.f);
        if (OUTF32) ((float*)Cp)[rb + colg] = vv;
        else ((u16*)Cp + (size_t)z * cZ)[rb + colg] = f2b(vv);
      }
    }
  }
}

// ---------------------------------------------------------------------------
// Attention: seq_len 3, H=8, DH=32, bf16 in/out. 8 sequences per block.
// ---------------------------------------------------------------------------
__global__ __launch_bounds__(256)
void attn(const bf16* __restrict__ qp, const bf16* __restrict__ kp,
          const bf16* __restrict__ vp, bf16* __restrict__ op)
{
  __shared__ __align__(16) u16 qs[6144], ks[6144], vs[6144];
  __shared__ float probs[8][8][9];
  const int tid = threadIdx.x;
  const size_t gbase = (size_t)blockIdx.x * 6144;   // 8 seq * 3 tok * 256
  const uint4* qg = (const uint4*)((const u16*)qp + gbase);
  const uint4* kg = (const uint4*)((const u16*)kp + gbase);
  const uint4* vg = (const uint4*)((const u16*)vp + gbase);
  for (int c = tid; c < 768; c += 256) {
    ((uint4*)qs)[c] = qg[c];
    ((uint4*)ks)[c] = kg[c];
    ((uint4*)vs)[c] = vg[c];
  }
  __syncthreads();
  if (tid < 64) {
    int s = tid >> 3, h = tid & 7;
    int base = s * 768 + h * 32;
    float sc[3][3];
    #pragma unroll
    for (int i = 0; i < 3; i++)
      #pragma unroll
      for (int j = 0; j < 3; j++) {
        float sum = 0.f;
        #pragma unroll
        for (int d = 0; d < 32; d++)
          sum += b2f(qs[base + i * 256 + d]) * b2f(ks[base + j * 256 + d]);
        sc[i][j] = sum * 0.17677669529663687f;   // DH^-0.5
      }
    #pragma unroll
    for (int i = 0; i < 3; i++) {
      float m = fmaxf(sc[i][0], fmaxf(sc[i][1], sc[i][2]));
      float e0 = __expf(sc[i][0] - m);
      float e1 = __expf(sc[i][1] - m);
      float e2 = __expf(sc[i][2] - m);
      float inv = 1.f / (e0 + e1 + e2);
      probs[s][h][i * 3 + 0] = e0 * inv;
      probs[s][h][i * 3 + 1] = e1 * inv;
      probs[s][h][i * 3 + 2] = e2 * inv;
    }
  }
  __syncthreads();
  u16* og = (u16*)op + gbase;
  for (int c = tid; c < 6144; c += 256) {
    int lrow = c >> 8, hd = c & 255;
    int s = lrow / 3, i = lrow - s * 3;
    int h = hd >> 5;
    float p0 = probs[s][h][i * 3 + 0];
    float p1 = probs[s][h][i * 3 + 1];
    float p2 = probs[s][h][i * 3 + 2];
    float o = p0 * b2f(vs[s * 768 + hd])
            + p1 * b2f(vs[s * 768 + 256 + hd])
            + p2 * b2f(vs[s * 768 + 512 + hd]);
    og[c] = f2b(o);
  }
}

// ---------------------------------------------------------------------------
// Final LN + mean over 3 tokens (f32 in, f32 out). 1 wave/seq, 4 seq/block.
// ---------------------------------------------------------------------------
__global__ __launch_bounds__(256)
void ln_final_mean(const float* __restrict__ xp, const float* __restrict__ gp,
                   const float* __restrict__ bp, float* __restrict__ outp)
{
  const int lane = threadIdx.x & 63;
  const int n = blockIdx.x * 4 + (threadIdx.x >> 6);
  float4 gv = *(const float4*)(gp + lane * 4);
  float4 bv4 = *(const float4*)(bp + lane * 4);
  float a0 = 0.f, a1 = 0.f, a2 = 0.f, a3 = 0.f;
  for (int t = 0; t < 3; t++) {
    float4 rv = *(const float4*)(xp + ((size_t)n * 3 + t) * 256 + lane * 4);
    float v0 = rv.x, v1 = rv.y, v2 = rv.z, v3 = rv.w;
    float s = v0 + v1 + v2 + v3;
    float q = v0 * v0 + v1 * v1 + v2 * v2 + v3 * v3;
    #pragma unroll
    for (int m = 32; m > 0; m >>= 1) {
      s += __shfl_xor(s, m, 64);
      q += __shfl_xor(q, m, 64);
    }
    float mean = s * (1.f / 256.f);
    float var = q * (1.f / 256.f) - mean * mean;
    float r = rsqrtf(var + 1e-5f);
    a0 += (v0 - mean) * r * gv.x + bv4.x;
    a1 += (v1 - mean) * r * gv.y + bv4.y;
    a2 += (v2 - mean) * r * gv.z + bv4.z;
    a3 += (v3 - mean) * r * gv.w + bv4.w;
  }
  const float third = 1.f / 3.f;
  float4 outv;
  outv.x = a0 * third;
  outv.y = a1 * third;
  outv.z = a2 * third;
  outv.w = a3 * third;
  *(float4*)(outp + (size_t)n * 256 + lane * 4) = outv;
}

// ---------------------------------------------------------------------------
extern "C" void kernel_launch(void* const* d_in, const int* in_sizes, int n_in,
                              void* d_out, int out_size, void* d_ws, size_t ws_size,
                              hipStream_t stream)
{
  const float* term = (const float*)d_in[0];
  const float* pred = (const float*)d_in[1];
  const float* Wq  = (const float*)d_in[2];
  const float* Wk  = (const float*)d_in[3];
  const float* Wv  = (const float*)d_in[4];
  const float* Wo  = (const float*)d_in[5];
  const float* bq  = (const float*)d_in[6];
  const float* bk  = (const float*)d_in[7];
  const float* bvv = (const float*)d_in[8];
  const float* bo  = (const float*)d_in[9];
  const float* ln1g = (const float*)d_in[10];
  const float* ln1b = (const float*)d_in[11];
  const float* ln2g = (const float*)d_in[12];
  const float* ln2b = (const float*)d_in[13];
  const float* W1  = (const float*)d_in[14];
  const float* b1  = (const float*)d_in[15];
  const float* W2  = (const float*)d_in[16];
  const float* b2  = (const float*)d_in[17];
  const float* lnfg = (const float*)d_in[18];
  const float* lnfb = (const float*)d_in[19];

  // --- choose chunk count from ws_size (deterministic; same every call).
  // Per chunk: x f32 (Mc*1024B) + h bf16 (Mc*512B) + q,k,v,o bf16 (Mc*2048B,
  // f aliases q..o). Weights/bias: 4 MB up front.
  int nch = 128;
  for (int c = 1; c <= 128; c *= 2) {
    size_t Mc = (size_t)MROWS / c;
    size_t need = 4ull * 1024 * 1024 + Mc * 3584ull;
    if (need <= ws_size) { nch = c; break; }
  }
  const size_t Mc = (size_t)MROWS / nch;     // multiple of 1152
  const int mBlocks = (int)(Mc / 128);

  char* ws = (char*)d_ws;
  bf16* wt   = (bf16*)ws;                    // 1572864 el (3 MB)
  float* bqkv = (float*)(ws + 3145728);      // 1536 f32
  float* x = (float*)(ws + 4194304);         // Mc*256 f32
  bf16* h = (bf16*)(x + Mc * 256);           // Mc*256 bf16
  bf16* q = h + Mc * 256;                    // q,k,v,o contiguous bf16
  bf16* v_ = q + 2 * Mc * 256;
  bf16* o = q + 3 * Mc * 256;
  bf16* f = q;                               // FFN hidden aliases q..o

  prep_weights<<<6145, 256, 0, stream>>>(Wq, Wk, Wv, Wo, W1, W2, bq, bk, bvv, wt, bqkv);

  const long long qkvZ = (long long)(Mc * 256);
  for (int ch = 0; ch < nch; ch++) {
    const int row0 = (int)(ch * Mc);
    // fused: build x rows + layer-0 LN1 -> h
    build_ln<<<(int)(Mc / 4), 256, 0, stream>>>(term, pred, ln1g, ln1b, x, h, row0);
    for (int l = 0; l < 2; l++) {
      const bf16* wl = wt + l * 786432;
      if (l > 0)
        ln_rows<<<(int)(Mc / 4), 256, 0, stream>>>(x, ln1g + l * 256, ln1b + l * 256, h);
      gemm_bt<0, 0, 0><<<dim3(mBlocks, 2, 3), 256, 0, stream>>>(
          h, wl, bqkv + l * 768, nullptr, q, 256, 256, 65536, 256, qkvZ);
      attn<<<(int)(Mc / 24), 256, 0, stream>>>(q, q + Mc * 256, v_, o);
      gemm_bt<1, 0, 1><<<dim3(mBlocks, 2, 1), 256, 0, stream>>>(
          o, wl + 196608, bo + l * 256, x, x, 256, 256, 0, 0, 0);
      ln_rows<<<(int)(Mc / 4), 256, 0, stream>>>(x, ln2g + l * 256, ln2b + l * 256, h);
      gemm_bt<0, 1, 0><<<dim3(mBlocks, 8, 1), 256, 0, stream>>>(
          h, wl + 262144, b1 + l * 1024, nullptr, f, 1024, 256, 0, 0, 0);
      gemm_bt<1, 0, 1><<<dim3(mBlocks, 2, 1), 256, 0, stream>>>(
          f, wl + 524288, b2 + l * 256, x, x, 256, 1024, 0, 0, 0);
    }
    ln_final_mean<<<(int)(Mc / 12), 256, 0, stream>>>(
        x, lnfg, lnfb, (float*)d_out + (size_t)(row0 / 3) * 256);
  }
}